// Round 6
// baseline (168.657 us; speedup 1.0000x reference)
//
#include <hip/hip_runtime.h>

// Problem: B=8, S=2048, H=1024, D=64. fp32 in, fp32 out.
// out = softmax_causal(q k^T) / sqrt(H) @ v   (softmax FIRST, then /32)

typedef float     f32x4 __attribute__((ext_vector_type(4)));
typedef _Float16  f16x8 __attribute__((ext_vector_type(8)));
typedef _Float16  f16x4 __attribute__((ext_vector_type(4)));

template<bool V> struct BoolT { static constexpr bool value = V; };

// ---------------------------------------------------------------------------
// Kernel 1: pack W{q,k,v} into MFMA B-fragment order (f16) via LDS transpose.
__global__ __launch_bounds__(256) void wt_prep(const float* __restrict__ Wq,
                                               const float* __restrict__ Wk,
                                               const float* __restrict__ Wv,
                                               _Float16* __restrict__ WtF) {
  const int w  = blockIdx.x >> 4;              // which W
  const int kt = blockIdx.x & 15;              // k-tile of 64
  const float* src = (w == 0) ? Wq : (w == 1 ? Wk : Wv);
  __shared__ _Float16 ls[64][72];              // [local k][n], padded
  const int t = threadIdx.x;
  {
    int rr = t >> 4;                           // 0..15
    int c4 = (t & 15) * 4;
    #pragma unroll
    for (int ri = 0; ri < 4; ++ri) {
      int k = rr + ri * 16;                    // local k 0..63
      f32x4 f = *(const f32x4*)&src[(size_t)(kt * 64 + k) * 64 + c4];
      #pragma unroll
      for (int j = 0; j < 4; ++j) ls[k][c4 + j] = (_Float16)f[j];
    }
  }
  __syncthreads();
  const int lane = t & 63, l16 = lane & 15, quad = lane >> 4;
  #pragma unroll
  for (int h = 0; h < 2; ++h) {
    int fid     = h * 4 + (t >> 6);            // 0..7
    int kstep_l = fid >> 2;                    // 0..1
    int ntl     = fid & 3;                     // 0..3
    int nt      = w * 4 + ntl;
    int kstep   = kt * 2 + kstep_l;
    f16x8 o;
    #pragma unroll
    for (int j = 0; j < 8; ++j) o[j] = ls[kstep_l * 32 + quad * 8 + j][ntl * 16 + l16];
    *(f16x8*)&WtF[((size_t)(kstep * 12 + nt) * 64 + lane) * 8] = o;
  }
}

// ---------------------------------------------------------------------------
// Kernel 2: QKV projection. XCD-aligned block remap kept (batch = bid&7).
__global__ __launch_bounds__(512, 4) void qkv_gemm(const float* __restrict__ x,
                                                   const _Float16* __restrict__ WtF,
                                                   const float* __restrict__ bq,
                                                   const float* __restrict__ bk,
                                                   const float* __restrict__ bv,
                                                   _Float16* __restrict__ qo,
                                                   _Float16* __restrict__ ko,
                                                   _Float16* __restrict__ vt) {
  __shared__ _Float16 xs[32 * 1024];           // exactly 64 KB
  const int tid  = threadIdx.x;
  const int wave = tid >> 6, lane = tid & 63;
  const int l16  = lane & 15, quad = lane >> 4;
  const int mhalf = wave >> 2;                 // 0..1
  const int ngrp  = wave & 3;                  // 0..3
  const int bid   = blockIdx.x;
  const int m0    = (((bid & 7) << 6) + (bid >> 3)) * 32;  // batch=bid&7, tile=bid>>3

  // --- stage x tile (fp32 -> f16), coalesced: 16-lane groups read 256B runs
  {
    int row   = tid >> 4;                      // 0..31
    int cbase = (tid & 15) * 4;
    const float* xrow = x + (size_t)(m0 + row) * 1024;
    int key = row & 7;
    #pragma unroll
    for (int j = 0; j < 16; ++j) {
      int col = cbase + j * 64;
      f32x4 f = *(const f32x4*)&xrow[col];
      f16x4 hh;
      #pragma unroll
      for (int e = 0; e < 4; ++e) hh[e] = (_Float16)f[e];
      int g   = col >> 3;                      // granule index 0..127
      int sub = col & 7;                       // 0 or 4
      *(f16x4*)&xs[(size_t)row * 1024 + (size_t)((g ^ key) << 3) + sub] = hh;
    }
  }
  __syncthreads();

  f32x4 acc0 = (f32x4){0.f,0.f,0.f,0.f};
  f32x4 acc1 = (f32x4){0.f,0.f,0.f,0.f};
  f32x4 acc2 = (f32x4){0.f,0.f,0.f,0.f};

  const int arow = mhalf * 16 + l16;
  const _Float16* abase = xs + (size_t)arow * 1024;
  const int akey = arow & 7;
  const _Float16* wbase = WtF + ((size_t)(ngrp * 3) * 64 + lane) * 8;

  #pragma unroll 4
  for (int kstep = 0; kstep < 32; ++kstep) {
    f16x8 a = *(const f16x8*)(abase + (((kstep * 4 + quad) ^ akey) << 3));
    const _Float16* wk = wbase + (size_t)kstep * (12 * 64 * 8);
    f16x8 b0 = *(const f16x8*)(wk);
    f16x8 b1 = *(const f16x8*)(wk + 512);
    f16x8 b2 = *(const f16x8*)(wk + 1024);
    acc0 = __builtin_amdgcn_mfma_f32_16x16x32_f16(a, b0, acc0, 0, 0, 0);
    acc1 = __builtin_amdgcn_mfma_f32_16x16x32_f16(a, b1, acc1, 0, 0, 0);
    acc2 = __builtin_amdgcn_mfma_f32_16x16x32_f16(a, b2, acc2, 0, 0, 0);
  }

  // --- epilogue: C/D col=lane&15, row=quad*4+r. Bias add, f16 write.
  f32x4 accs[3] = {acc0, acc1, acc2};
  #pragma unroll
  for (int i = 0; i < 3; ++i) {
    int nt  = ngrp * 3 + i;
    int col = nt * 16 + l16;
    float bias = (nt < 4) ? bq[col] : (nt < 8) ? bk[col - 64] : bv[col - 128];
    #pragma unroll
    for (int r = 0; r < 4; ++r) {
      int m = m0 + mhalf * 16 + quad * 4 + r;  // global row = b*2048+s
      _Float16 hv = (_Float16)(accs[i][r] + bias);
      if (nt < 4)      qo[(size_t)m * 64 + col] = hv;
      else if (nt < 8) ko[(size_t)m * 64 + (col - 64)] = hv;
      else {                                   // v stored transposed: vt[b][d][s]
        int b = m >> 11, s = m & 2047;
        vt[((size_t)b * 64 + (col - 128)) * 2048 + s] = hv;
      }
    }
  }
}

// ---------------------------------------------------------------------------
// Kernel 3a: attention PARTIALS, fully flattened split-KV.
// Work item = (batch b, q-tile qt of 16 rows, 128-kv chunk c). One item per
// WAVE, no kv loop, no online softmax, no inter-wave coupling, no barrier.
// Items per batch: sum_qt ceil((qt+1)/8) = 1088; total 8704 = 2176 blocks x 4.
// Group g = qt>>3 has 8 tiles x (g+1) chunks; items before group g = 4g(g+1).
// Every q-row has kv0 <= qrow, so the chunk max m is always finite.
// Each wave: load Q(2)+K(16)+V(16), QK (swapped operands -> per-lane kv-row
// stats), plain per-chunk softmax, PV, write 4KB fp32 partial O + (m,l).
// Kernel 3b merges <=16 partials per (b,qt) with LSE weighting.
__global__ __launch_bounds__(256, 3) void attn_part(const _Float16* __restrict__ q,
                                                    const _Float16* __restrict__ k,
                                                    const _Float16* __restrict__ vt,
                                                    float* __restrict__ po,
                                                    float* __restrict__ pml) {
  const int tid  = threadIdx.x;
  const int wave = tid >> 6, lane = tid & 63;
  const int l16  = lane & 15, quad = lane >> 4;
  const int item = blockIdx.x * 4 + wave;      // grid sized exactly: item < 8704

  // ---- decode item -> (b, qt, c), integer-only ----
  const int b = item / 1088;
  const int r = item - b * 1088;
  // solve max g with 4g(g+1) <= r: integer isqrt seed + 2 exact corrections
  int g = 0;
  { // isqrt(r/4 + small) style seed: g ~ (sqrt(r+1)-1)/2 computed in int
    int lo = 0, hi = 16;                       // g in [0,15] for r < 1088
    while (lo < hi) {                          // 4-step binary search, exact
      int mid = (lo + hi + 1) >> 1;
      if (4 * mid * (mid + 1) <= r) lo = mid; else hi = mid - 1;
    }
    g = lo;
  }
  const int rr    = r - 4 * g * (g + 1);
  const int n     = g + 1;                     // chunks per tile in this group
  const int tile  = rr / n;                    // 0..7
  const int c     = rr - tile * n;             // chunk index 0..n-1
  const int qt    = 8 * g + tile;
  const int q0    = qt * 16;
  const int kv0   = c * 128;
  const int kvlen = min(128, q0 + 16 - kv0);   // 16..128, multiple of 16

  __shared__ _Float16 P[4][16][136];           // per-wave P^T buffer [q][kv]
  __shared__ float    ob[4][16][68];           // per-wave O transpose buffer

  const _Float16* qb = q  + (size_t)b * 2048 * 64;
  const _Float16* kb = k  + (size_t)b * 2048 * 64;
  const _Float16* vb = vt + (size_t)b * 64 * 2048;

  f16x8 qf0 = *(const f16x8*)&qb[(q0 + l16) * 64 + quad * 8];
  f16x8 qf1 = *(const f16x8*)&qb[(q0 + l16) * 64 + 32 + quad * 8];

  const float L2E = 1.44269504088896340736f;
  const int qrow  = q0 + l16;

  float m, l;
  f32x4 o[4];

  auto body = [&](auto fullc) {
    constexpr bool FULL = decltype(fullc)::value;

    // ---- issue ALL K loads (16), then ALL V loads (16) ----
    f16x8 kf[8][2];
    #pragma unroll
    for (int t = 0; t < 8; ++t)
      if (FULL || t * 16 < kvlen) {            // wave-uniform
        kf[t][0] = *(const f16x8*)&kb[(kv0 + t * 16 + l16) * 64 + quad * 8];
        kf[t][1] = *(const f16x8*)&kb[(kv0 + t * 16 + l16) * 64 + 32 + quad * 8];
      }
    f16x8 vf[4][4];
    #pragma unroll
    for (int ks = 0; ks < 4; ++ks)
      if (FULL || ks * 32 < kvlen) {           // wave-uniform
        #pragma unroll
        for (int dt = 0; dt < 4; ++dt)
          vf[ks][dt] = *(const f16x8*)&vb[(size_t)(dt * 16 + l16) * 2048 + kv0 + ks * 32 + quad * 8];
      }

    // ---- QK^T (swapped): sc[t][r] = S[kv0+t*16+quad*4+r][q0+l16] ----
    f32x4 sc[8];
    #pragma unroll
    for (int t = 0; t < 8; ++t) {
      const int kvc = kv0 + t * 16;
      f32x4 cc;
      if (FULL || t * 16 < kvlen) {
        cc = (f32x4){0.f, 0.f, 0.f, 0.f};
        cc = __builtin_amdgcn_mfma_f32_16x16x32_f16(kf[t][0], qf0, cc, 0, 0, 0);
        cc = __builtin_amdgcn_mfma_f32_16x16x32_f16(kf[t][1], qf1, cc, 0, 0, 0);
        if (kvc + 15 > q0) {                   // only the diagonal 16-kv tile
          #pragma unroll
          for (int rr2 = 0; rr2 < 4; ++rr2)
            if (kvc + quad * 4 + rr2 > qrow) cc[rr2] = -1e30f;
        }
      } else {
        cc = (f32x4){-1e30f, -1e30f, -1e30f, -1e30f};
      }
      sc[t] = cc;
    }

    // ---- plain softmax over this chunk (single pass; merge does LSE) ----
    float mx = -1e30f;
    #pragma unroll
    for (int t = 0; t < 8; ++t)
      mx = fmaxf(mx, fmaxf(fmaxf(sc[t][0], sc[t][1]), fmaxf(sc[t][2], sc[t][3])));
    mx = fmaxf(mx, __shfl_xor(mx, 16, 64));
    mx = fmaxf(mx, __shfl_xor(mx, 32, 64));
    m = mx;                                    // finite: kv0 <= qrow always

    float s = 0.f;
    #pragma unroll
    for (int t = 0; t < 8; ++t) {
      #pragma unroll
      for (int rr2 = 0; rr2 < 4; ++rr2) sc[t][rr2] = exp2f((sc[t][rr2] - m) * L2E);
      s += (sc[t][0] + sc[t][1]) + (sc[t][2] + sc[t][3]);
    }
    s += __shfl_xor(s, 16, 64);
    s += __shfl_xor(s, 32, 64);
    l = s;

    // ---- P^T -> LDS in B-frag orientation (b64 writes), drain lgkm ----
    #pragma unroll
    for (int t = 0; t < 8; ++t) {
      f16x4 ph;
      #pragma unroll
      for (int rr2 = 0; rr2 < 4; ++rr2) ph[rr2] = (_Float16)sc[t][rr2];
      *(f16x4*)&P[wave][l16][t * 16 + quad * 4] = ph;
    }
    asm volatile("s_waitcnt lgkmcnt(0)" ::: "memory");

    // ---- PV: o[d][q] += V^T-frag x P^T-frag ----
    #pragma unroll
    for (int i = 0; i < 4; ++i) o[i] = (f32x4){0.f, 0.f, 0.f, 0.f};
    #pragma unroll
    for (int ks = 0; ks < 4; ++ks)
      if (FULL || ks * 32 < kvlen) {
        f16x8 pf = *(const f16x8*)&P[wave][l16][ks * 32 + quad * 8];
        #pragma unroll
        for (int dt = 0; dt < 4; ++dt)
          o[dt] = __builtin_amdgcn_mfma_f32_16x16x32_f16(vf[ks][dt], pf, o[dt], 0, 0, 0);
      }
  };
  if (kvlen == 128) body(BoolT<true>{});
  else              body(BoolT<false>{});

  // ---- publish: o row=d=dt*16+quad*4+r, col=q=l16 -> LDS transpose ----
  #pragma unroll
  for (int dt = 0; dt < 4; ++dt)
    *(f32x4*)&ob[wave][l16][dt * 16 + quad * 4] = o[dt];
  if (quad == 0) {
    pml[(size_t)item * 32 + l16]      = m;
    pml[(size_t)item * 32 + 16 + l16] = l;
  }
  asm volatile("s_waitcnt lgkmcnt(0)" ::: "memory");
  {
    // coalesced 4KB store: lane -> row = lane>>2 (q), 16 floats of d
    const int row = lane >> 2, c4 = (lane & 3) * 16;
    float* dst = po + (size_t)item * 1024 + row * 64 + c4;
    #pragma unroll
    for (int j = 0; j < 4; ++j)
      *(f32x4*)&dst[j * 4] = *(const f32x4*)&ob[wave][row][c4 + j * 4];
  }
}

// ---------------------------------------------------------------------------
// Kernel 3b: merge partials per (b, qt): <=16 splits, LSE weighting.
// Grid 1024 = 8 b x 128 qt, 256 threads; thread -> (q = t>>4, d0 = (t&15)*4).
__global__ __launch_bounds__(256) void attn_merge(const float* __restrict__ po,
                                                  const float* __restrict__ pml,
                                                  float* __restrict__ out) {
  const int blk = blockIdx.x;
  const int b   = blk >> 7, qt = blk & 127;
  const int g   = qt >> 3, n = g + 1;
  const int base = b * 1088 + 4 * g * (g + 1) + (qt & 7) * n;
  const int t   = threadIdx.x;
  const int qr  = t >> 4, d0 = (t & 15) * 4;
  const float L2E = 1.44269504088896340736f;

  const float* mlp = pml + (size_t)base * 32 + qr;
  float M = -1e30f;
  for (int it = 0; it < n; ++it) M = fmaxf(M, mlp[it * 32]);

  float L = 0.f;
  f32x4 acc = (f32x4){0.f, 0.f, 0.f, 0.f};
  for (int it = 0; it < n; ++it) {
    float w = exp2f((mlp[it * 32] - M) * L2E);
    L += w * mlp[it * 32 + 16];
    f32x4 p = *(const f32x4*)&po[((size_t)(base + it) * 16 + qr) * 64 + d0];
    #pragma unroll
    for (int jj = 0; jj < 4; ++jj) acc[jj] += w * p[jj];
  }
  const float inv = 1.0f / (L * 32.0f);        // sqrt(H)=32 applied AFTER softmax
  f32x4 res;
  #pragma unroll
  for (int jj = 0; jj < 4; ++jj) res[jj] = acc[jj] * inv;
  *(f32x4*)&out[((size_t)b * 2048 + qt * 16 + qr) * 64 + d0] = res;
}

// ---------------------------------------------------------------------------
extern "C" void kernel_launch(void* const* d_in, const int* in_sizes, int n_in,
                              void* d_out, int out_size, void* d_ws, size_t ws_size,
                              hipStream_t stream) {
  const float* x  = (const float*)d_in[0];
  const float* Wq = (const float*)d_in[1];
  const float* bq = (const float*)d_in[2];
  const float* Wk = (const float*)d_in[3];
  const float* bk = (const float*)d_in[4];
  const float* Wv = (const float*)d_in[5];
  const float* bv = (const float*)d_in[6];
  float* out = (float*)d_out;

  // ws layout: f16 region: WtF 192*1024 | q 16384*64 | k 16384*64 | vt 8*64*2048
  // then f32 region: po 8704*1024 (35.7MB) | pml 8704*32 (1.1MB). Total ~44MB.
  _Float16* WtF = (_Float16*)d_ws;
  _Float16* qo  = WtF + 192 * 1024;
  _Float16* ko  = qo + 16384 * 64;
  _Float16* vt  = ko + 16384 * 64;
  float*    po  = (float*)(vt + 8 * 64 * 2048);
  float*    pml = po + (size_t)8704 * 1024;

  hipLaunchKernelGGL(wt_prep,    dim3(48),   dim3(256), 0, stream, Wq, Wk, Wv, WtF);
  hipLaunchKernelGGL(qkv_gemm,   dim3(512),  dim3(512), 0, stream, x, WtF, bq, bk, bv, qo, ko, vt);
  hipLaunchKernelGGL(attn_part,  dim3(2176), dim3(256), 0, stream, qo, ko, vt, po, pml);
  hipLaunchKernelGGL(attn_merge, dim3(1024), dim3(256), 0, stream, po, pml, out);
}